// Round 7
// baseline (175.732 us; speedup 1.0000x reference)
//
#include <hip/hip_runtime.h>
#include <hip/hip_fp16.h>

// BackProjectionLinear: out[b,p] = sum_d apod[d] * lerp(sino[b,d], k[p,d], a[p,d]) / 63.5
// B=4, N_DET=128, N_T=2048, pixels=65536.
//
// R7: R6 showed the compiler won't hold a cross-barrier software pipeline
// (it pinned 64 VGPRs and sank the prefetch loads; nt-lut loads added 27MB
// of refetch). Revert to R4's simple serial-phase structure and get the
// latency overlap from OCCUPANCY instead:
//  - LDS 32KB: [2 dets][2048 t][batches01, batches23] half2. 4 phases over
//    det-pairs, each stages 2 dets x ALL 4 batches -> gather decodes each
//    (px,det) lut entry once and reads 16B (2x ds_read_b64).
//  - __launch_bounds__(512,8) -> <=64 VGPR -> 4 blocks/CU, 32 waves/CU
//    (vs R4's 2 blocks / 16 waves). Blocks' barriers interleave.
//  - lut: full 64B line per pixel in regs (8 float4 = 32 VGPR), plain loads,
//    fetched exactly once (R3 lesson). apod -> SGPR via readfirstlane.
//  - bid%16 = octet (bid%8 ~ XCD) -> sino rows L2-pinned per XCD.
//  - atomicAdd partials into zeroed d_out at end (16 blocks per element).

#define NB      4
#define NDET    128
#define NT      2048
#define NPIX    65536
#define DBLOCK  8                    // dets per block = one 64B lut line
#define DPH     2                    // dets per phase
#define NPHASE  4
#define PTILE   1024
#define THREADS 512
#define PXPT    (PTILE / THREADS)    // 2 pixels per thread

__global__ __launch_bounds__(THREADS, 8)
void bp_kernel(const float* __restrict__ sino,
               const float* __restrict__ lut,
               float* __restrict__ out) {
    // [dl][t][c]: c=0 -> half2(b0,b1), c=1 -> half2(b2,b3). 32 KB.
    __shared__ __half2 lds[DPH][NT][2];

    const int tid   = threadIdx.x;
    const int octet = blockIdx.x & 15;   // bid%8 ~ XCD pinning
    const int tile  = blockIdx.x >> 4;   // 0..63
    const int d0    = octet * DBLOCK;
    const int px0   = tile * PTILE;

    // apod in SGPRs (wave-uniform) to stay under the 64-VGPR budget
    float apod[DBLOCK];
#pragma unroll
    for (int j = 0; j < DBLOCK; ++j) {
        float x = (float)(d0 + j) * (6.28318530717958647692f / 127.0f);
        float v = 0.5f - 0.5f * __cosf(x);
        apod[j] = __int_as_float(__builtin_amdgcn_readfirstlane(__float_as_int(v)));
    }

    // ---- full 64B lut line per pixel, loaded once (32 VGPRs) ----
    // L[i][q] = (k,a) for dets d0+2q, d0+2q+1 ; phase ph consumes L[i][ph].
    float4 L[PXPT][NPHASE];
#pragma unroll
    for (int i = 0; i < PXPT; ++i) {
        const float4* lp = (const float4*)
            (lut + ((size_t)(px0 + tid + i * THREADS) * NDET + d0) * 2);
#pragma unroll
        for (int q = 0; q < NPHASE; ++q) L[i][q] = lp[q];
    }

    float acc[PXPT][NB];
#pragma unroll
    for (int i = 0; i < PXPT; ++i)
#pragma unroll
        for (int b = 0; b < NB; ++b) acc[i][b] = 0.0f;

    const float4* s4 = (const float4*)sino;

    for (int ph = 0; ph < NPHASE; ++ph) {
        const int dg0 = d0 + ph * DPH;
        if (ph) __syncthreads();          // prior-phase readers done

        // ---- stage 2 dets x 4 batches x 2048 t ----
        // items: 2 dets x 512 t4 = 1024 -> 2 iters/thread.
        for (int f = tid; f < DPH * (NT / 4); f += THREADS) {
            int dl = f >> 9;              // 0..1
            int t4 = f & 511;
            size_t base = ((size_t)dg0 + dl) * (NT / 4) + t4;
            float4 v0 = s4[base];
            float4 v1 = s4[base + (size_t)1 * NDET * (NT / 4)];
            float4 v2 = s4[base + (size_t)2 * NDET * (NT / 4)];
            float4 v3 = s4[base + (size_t)3 * NDET * (NT / 4)];
            __half2* dst = &lds[dl][t4 * 4][0];   // 32B contiguous
            dst[0] = __floats2half2_rn(v0.x, v1.x);
            dst[1] = __floats2half2_rn(v2.x, v3.x);
            dst[2] = __floats2half2_rn(v0.y, v1.y);
            dst[3] = __floats2half2_rn(v2.y, v3.y);
            dst[4] = __floats2half2_rn(v0.z, v1.z);
            dst[5] = __floats2half2_rn(v2.z, v3.z);
            dst[6] = __floats2half2_rn(v0.w, v1.w);
            dst[7] = __floats2half2_rn(v2.w, v3.w);
        }
        __syncthreads();

        // ---- gather: 2 dets x 2 px/thread; one lut decode per (px,det) ----
#pragma unroll
        for (int i = 0; i < PXPT; ++i) {
            float4 Lq = L[i][ph];
#pragma unroll
            for (int h = 0; h < 2; ++h) {
                float kf = h ? Lq.z : Lq.x;
                float af = h ? Lq.w : Lq.y;
                int k = (int)kf;
                bool valid = (unsigned)k < (unsigned)(NT - 1);
                float w  = valid ? apod[ph * DPH + h] : 0.0f;
                int  k0  = valid ? k : 0;
                const __half2* q = &lds[h][k0][0];
                __half2 s0a = q[0], s0b = q[1];   // t=k0:   b01, b23
                __half2 s1a = q[2], s1b = q[3];   // t=k0+1: b01, b23
                __half2 a2  = __float2half2_rn(af);
                __half2 ska = __hfma2(a2, __hsub2(s1a, s0a), s0a);
                __half2 skb = __hfma2(a2, __hsub2(s1b, s0b), s0b);
                float2 fa = __half22float2(ska);
                float2 fb = __half22float2(skb);
                acc[i][0] = fmaf(w, fa.x, acc[i][0]);
                acc[i][1] = fmaf(w, fa.y, acc[i][1]);
                acc[i][2] = fmaf(w, fb.x, acc[i][2]);
                acc[i][3] = fmaf(w, fb.y, acc[i][3]);
            }
        }
    }

    // ---- emit partial sums (16 octet-blocks contribute per output) ----
    const float inv_norm = 1.0f / 63.5f;   // sum(apod) == 63.5 exactly
#pragma unroll
    for (int i = 0; i < PXPT; ++i) {
        const int px = px0 + tid + i * THREADS;
#pragma unroll
        for (int b = 0; b < NB; ++b) {
            atomicAdd(&out[(size_t)b * NPIX + px], acc[i][b] * inv_norm);
        }
    }
}

extern "C" void kernel_launch(void* const* d_in, const int* in_sizes, int n_in,
                              void* d_out, int out_size, void* d_ws, size_t ws_size,
                              hipStream_t stream) {
    const float* sino = (const float*)d_in[0];
    const float* lut  = (const float*)d_in[1];
    float* out = (float*)d_out;

    (void)hipMemsetAsync(d_out, 0, (size_t)out_size * sizeof(float), stream);

    // 16 octets x 64 pixel tiles = 1024 blocks -> 4 blocks/CU (32KB LDS, 64 VGPR)
    bp_kernel<<<dim3(1024), dim3(THREADS), 0, stream>>>(sino, lut, out);
}

// Round 8
// 127.140 us; speedup vs baseline: 1.3822x; 1.3822x over previous
//
#include <hip/hip_runtime.h>
#include <hip/hip_fp16.h>

// BackProjectionLinear: out[b,p] = sum_d apod[d] * lerp(sino[b,d], k[p,d], a[p,d]) / 63.5
// B=4, N_DET=128, N_T=2048, pixels=65536.
//
// R8: R7's launch_bounds(512,8) made the allocator squeeze to 32 VGPR and
// spill the lut array (WRITE 106MB, FETCH 166MB). Keep R4's register
// structure EXACTLY (52 VGPR, no spill, launch_bounds(512,4)) and get
// occupancy from LDS instead: 32KB buffer -> 4 blocks/CU = 32 waves/CU
// (R4: 64KB -> 2 blocks, 16 waves, both pipes idle at 34% occ).
//  - 4 phases = (batch-pair) x (det-half): stage 4 dets x 2 batches x 2048 t
//    as half2[dl][t] = 32KB. Same total staging/lut/gather work as R4.
//  - lut: full 64B line per pixel in regs (8 float4 = 32 VGPR), plain loads,
//    fetched exactly once.
//  - Staging: thread owns (dl,t4): 2 coalesced float4 loads + 1 aligned
//    ds_write_b128 (conflict-free).
//  - Gather: bank = k%32, random k -> ~4/bank = 1.58x (acceptable, m136).
//  - bid%16 = octet (bid%8 ~ XCD) -> sino rows L2-pinned per XCD.
//  - atomicAdd partials into zeroed d_out at end (16 blocks per element).

#define NB      4
#define NDET    128
#define NT      2048
#define NPIX    65536
#define DBLOCK  8                    // dets per block = one 64B lut line
#define DPH     4                    // dets per phase (det-half)
#define NPHASE  4                    // (batch-pair) x (det-half)
#define PTILE   1024
#define THREADS 512
#define PXPT    (PTILE / THREADS)    // 2 pixels per thread

__global__ __launch_bounds__(THREADS, 4)
void bp_kernel(const float* __restrict__ sino,
               const float* __restrict__ lut,
               float* __restrict__ out) {
    // [dl (0..3)][t] half2 = (b_even, b_odd) for the current batch-pair. 32 KB.
    __shared__ __half2 lds[DPH][NT];

    const int tid   = threadIdx.x;
    const int octet = blockIdx.x & 15;   // bid%8 ~ XCD pinning
    const int tile  = blockIdx.x >> 4;   // 0..63
    const int d0    = octet * DBLOCK;
    const int px0   = tile * PTILE;

    float apod[DBLOCK];
#pragma unroll
    for (int j = 0; j < DBLOCK; ++j) {
        float x = (float)(d0 + j) * (6.28318530717958647692f / 127.0f);
        apod[j] = 0.5f - 0.5f * __cosf(x);
    }

    // ---- full 64B lut line per pixel, loaded once (32 VGPRs, as R4) ----
    // L[i][q] = (k,a) for dets d0+2q, d0+2q+1. Det-half dh uses q=2dh, 2dh+1.
    float4 L[PXPT][4];
#pragma unroll
    for (int i = 0; i < PXPT; ++i) {
        const float4* lp = (const float4*)
            (lut + ((size_t)(px0 + tid + i * THREADS) * NDET + d0) * 2);
#pragma unroll
        for (int q = 0; q < 4; ++q) L[i][q] = lp[q];
    }

    float acc[PXPT][NB];
#pragma unroll
    for (int i = 0; i < PXPT; ++i)
#pragma unroll
        for (int b = 0; b < NB; ++b) acc[i][b] = 0.0f;

    const float4* s4 = (const float4*)sino;

    for (int ph = 0; ph < NPHASE; ++ph) {
        const int bp  = ph >> 1;          // batch pair: batches 2bp, 2bp+1
        const int dh  = ph & 1;           // det half
        const int b0  = bp * 2;
        const int dg0 = d0 + dh * DPH;
        if (ph) __syncthreads();          // prior-phase readers done

        // ---- stage 4 dets x 2 batches x 2048 t as half2 ----
        // items: 4 dets x 512 t4 = 2048 -> 4 iters/thread, 2 float4 loads each.
        for (int f = tid; f < DPH * (NT / 4); f += THREADS) {
            int dl = f >> 9;              // 0..3
            int t4 = f & 511;
            size_t row = ((size_t)b0 * NDET + dg0 + dl) * (NT / 4) + t4;
            float4 ve = s4[row];
            float4 vo = s4[row + (size_t)NDET * (NT / 4)];
            __half2* dst = &lds[dl][t4 * 4];
            dst[0] = __floats2half2_rn(ve.x, vo.x);
            dst[1] = __floats2half2_rn(ve.y, vo.y);
            dst[2] = __floats2half2_rn(ve.z, vo.z);
            dst[3] = __floats2half2_rn(ve.w, vo.w);
        }
        __syncthreads();

        // ---- gather: 4 dets x 2 px/thread ----
#pragma unroll
        for (int i = 0; i < PXPT; ++i) {
#pragma unroll
            for (int q2 = 0; q2 < 2; ++q2) {
                float4 Lq = L[i][dh * 2 + q2];
#pragma unroll
                for (int h = 0; h < 2; ++h) {
                    float kf = h ? Lq.z : Lq.x;
                    float af = h ? Lq.w : Lq.y;
                    int   dl = q2 * 2 + h;
                    int k = (int)kf;
                    bool valid = (unsigned)k < (unsigned)(NT - 1);
                    float w  = valid ? apod[dh * DPH + dl] : 0.0f;
                    int  k0  = valid ? k : 0;
                    __half2 s0v = lds[dl][k0];
                    __half2 s1v = lds[dl][k0 + 1];
                    __half2 a2  = __float2half2_rn(af);
                    __half2 sk  = __hfma2(a2, __hsub2(s1v, s0v), s0v);
                    float2  fv  = __half22float2(sk);
                    acc[i][b0 + 0] = fmaf(w, fv.x, acc[i][b0 + 0]);
                    acc[i][b0 + 1] = fmaf(w, fv.y, acc[i][b0 + 1]);
                }
            }
        }
    }

    // ---- emit partial sums (16 octet-blocks contribute per output) ----
    const float inv_norm = 1.0f / 63.5f;   // sum(apod) == 63.5 exactly
#pragma unroll
    for (int i = 0; i < PXPT; ++i) {
        const int px = px0 + tid + i * THREADS;
#pragma unroll
        for (int b = 0; b < NB; ++b) {
            atomicAdd(&out[(size_t)b * NPIX + px], acc[i][b] * inv_norm);
        }
    }
}

extern "C" void kernel_launch(void* const* d_in, const int* in_sizes, int n_in,
                              void* d_out, int out_size, void* d_ws, size_t ws_size,
                              hipStream_t stream) {
    const float* sino = (const float*)d_in[0];
    const float* lut  = (const float*)d_in[1];
    float* out = (float*)d_out;

    (void)hipMemsetAsync(d_out, 0, (size_t)out_size * sizeof(float), stream);

    // 16 octets x 64 pixel tiles = 1024 blocks -> 4 blocks/CU (32KB LDS)
    bp_kernel<<<dim3(1024), dim3(THREADS), 0, stream>>>(sino, lut, out);
}